// Round 9
// baseline (20.817 us; speedup 1.0000x reference)
//
#include <hip/hip_runtime.h>
#include <math.h>

// RDF with Gaussian smearing, N=512 points, 400 bins. Two dispatches:
// K1: NPART blocks x 256 thr histogram unordered pairs into LDS (Gaussian via
//     multiplicative recurrence, fixed 8-bin unrolled window), store partials.
// K2: 1 block reduces NPART partials, normalizes, writes count/bins/rdf.
// out layout: count[0..399], bins[400..800] (401 vals), rdf[801..1200]
// R9 = R8 structure, NPART 128->256 (use all CUs), window 9->8 bins (CUT 3.5).
#define NBINS 400
#define NPTS  512
#define RMAXF 13.635f
#define BOXF  (2.0f * RMAXF)
#define TPB   256

template <int NPART>
__global__ __launch_bounds__(TPB) void rdf_hist(const float* __restrict__ pos,
                                                float* __restrict__ part) {
    __shared__ float hist[NBINS];
    const int tid = threadIdx.x;
    for (int b = tid; b < NBINS; b += TPB) hist[b] = 0.0f;
    __syncthreads();

    const float inv_w = 399.0f / RMAXF;     // 1/width
    // E(b)=exp(-0.5*u^2), u = c-b (bin-width units). Recurrence along b:
    //   E <- E*F,  F <- F*e^-1,  E0=exp2(-0.5*log2e*u0^2), F0=exp2(log2e*(u0-0.5)).
    const float C2E = -0.72134752f;         // -0.5*log2(e)
    const float C2F = 1.44269504f;          // log2(e)
    const float KE  = 0.36787944f;          // e^-1

    // Unordered pairs (ordered histogram = 2x this; factor cancels in
    // count/total): slot p -> i = p>>8, k = (p&255)+1, j = (i+k) mod 512.
    // k==256 pairs appear for both endpoints; keep only i<256.
    const int total = NPTS * 256;           // 131072 slots
    for (int p = blockIdx.x * TPB + tid; p < total; p += NPART * TPB) {
        const int i = p >> 8;
        const int k = (p & 255) + 1;
        const bool valid = !(k == 256 && i >= 256);
        const int j = (i + k) & (NPTS - 1);
        float dx = fabsf(pos[3*i+0] - pos[3*j+0]);
        float dy = fabsf(pos[3*i+1] - pos[3*j+1]);
        float dz = fabsf(pos[3*i+2] - pos[3*j+2]);
        if (dx > RMAXF) dx = BOXF - dx;     // minimum-image fold
        if (dy > RMAXF) dy = BOXF - dy;
        if (dz > RMAXF) dz = BOXF - dz;
        const float dist = sqrtf(dx*dx + dy*dy + dz*dz);
        const float c = dist * inv_w;       // position in bin-width units
        float b0f = ceilf(c - 3.5f);        // +/-3.5 sigma window, 8 bins
        if (b0f < 0.0f) b0f = 0.0f;
        if (valid && dist > 0.0f && b0f <= 399.0f) {
            const int b0 = (int)b0f;
            const float u = c - b0f;        // u0 in [0, 3.5]
            float E = exp2f(C2E * u * u);
            float F = exp2f(C2F * (u - 0.5f));
            const int rmax = (NBINS - 1) - b0;
            #pragma unroll
            for (int r = 0; r < 8; ++r) {
                if (r <= rmax)
                    unsafeAtomicAdd(&hist[b0 + r], E);
                E *= F;
                F *= KE;
            }
        }
    }
    __syncthreads();
    for (int b = tid; b < NBINS; b += TPB)
        part[blockIdx.x * NBINS + b] = hist[b];
}

template <int NPART>
__global__ __launch_bounds__(512) void rdf_final(const float* __restrict__ part,
                                                 float* __restrict__ out) {
    __shared__ float ssum[8];
    const int t = threadIdx.x;

    float v = 0.0f;
    if (t < NBINS) {
        #pragma unroll 16
        for (int p = 0; p < NPART; ++p) v += part[p * NBINS + t];
    }

    // total = sum over bins: wave(64) reduce then cross-wave via LDS
    float s = v;
    #pragma unroll
    for (int o = 32; o > 0; o >>= 1) s += __shfl_down(s, o, 64);
    if ((t & 63) == 0) ssum[t >> 6] = s;
    __syncthreads();
    if (t == 0) {
        float tot = 0.0f;
        #pragma unroll
        for (int w = 0; w < 8; ++w) tot += ssum[w];
        ssum[0] = tot;
    }
    __syncthreads();
    const float tot = ssum[0];

    if (t < NBINS) {
        const float cf = v / tot;
        out[t] = cf;                                   // count (normalized)
        // rdf = cf * V/vol_bin = cf * 400^3 / (3b^2+3b+1) (exact integer form)
        const float denom = (3.0f * t * t + 3.0f * t + 1.0f);
        out[801 + t] = cf * (400.0f * 400.0f * 400.0f) / denom;
    }
    if (t < NBINS + 1) {
        out[NBINS + t] = (float)t * (RMAXF / 400.0f);  // bins = linspace(0, R_MAX, 401)
    }
}

extern "C" void kernel_launch(void* const* d_in, const int* in_sizes, int n_in,
                              void* d_out, int out_size, void* d_ws, size_t ws_size,
                              hipStream_t stream) {
    const float* pos = (const float*)d_in[0];
    float* out = (float*)d_out;
    float* part = (float*)d_ws;   // NPART*NBINS floats, fully overwritten each call

    if (ws_size >= (size_t)256 * NBINS * sizeof(float)) {
        rdf_hist<256><<<256, TPB, 0, stream>>>(pos, part);
        rdf_final<256><<<1, 512, 0, stream>>>(part, out);
    } else {
        rdf_hist<128><<<128, TPB, 0, stream>>>(pos, part);
        rdf_final<128><<<1, 512, 0, stream>>>(part, out);
    }
}

// Round 10
// 16.596 us; speedup vs baseline: 1.2544x; 1.2544x over previous
//
#include <hip/hip_runtime.h>
#include <hip/hip_bf16.h>
#include <math.h>

// RDF with Gaussian smearing, N=512 points, 400 bins. Two dispatches:
// K1: 128 blocks x 256 thr histogram unordered pairs into LDS (Gaussian via
//     multiplicative recurrence, 7-bin window = +/-3 sigma), bf16 partials.
// K2: 1 block reduces 128 bf16 partials, normalizes, writes count/bins/rdf.
// out layout: count[0..399], bins[400..800] (401 vals), rdf[801..1200]
// R10 = R6 structure (best, 18.8us) + CUT 4.0->3.0 + bf16 partials.
#define NBINS 400
#define NPTS  512
#define RMAXF 13.635f
#define BOXF  (2.0f * RMAXF)
#define NPART 128
#define TPB   256

__global__ __launch_bounds__(TPB) void rdf_hist(const float* __restrict__ pos,
                                                __hip_bfloat16* __restrict__ part) {
    __shared__ float hist[NBINS];
    const int tid = threadIdx.x;
    for (int b = tid; b < NBINS; b += TPB) hist[b] = 0.0f;
    __syncthreads();

    const float inv_w = 399.0f / RMAXF;     // 1/width
    // E(b)=exp(-0.5*u^2), u = c-b (bin-width units). Recurrence along b:
    //   E <- E*F,  F <- F*e^-1,  E0=exp2(-0.5*log2e*u0^2), F0=exp2(log2e*(u0-0.5)).
    const float C2E = -0.72134752f;         // -0.5*log2(e)
    const float C2F = 1.44269504f;          // log2(e)
    const float KE  = 0.36787944f;          // e^-1

    // Unordered pairs (ordered histogram = 2x this; factor cancels in
    // count/total): slot p -> i = p>>8, k = (p&255)+1, j = (i+k) mod 512.
    // k==256 pairs appear for both endpoints; keep only i<256.
    const int total = NPTS * 256;           // 131072 slots
    for (int p = blockIdx.x * TPB + tid; p < total; p += NPART * TPB) {
        const int i = p >> 8;
        const int k = (p & 255) + 1;
        const bool valid = !(k == 256 && i >= 256);
        const int j = (i + k) & (NPTS - 1);
        float dx = fabsf(pos[3*i+0] - pos[3*j+0]);
        float dy = fabsf(pos[3*i+1] - pos[3*j+1]);
        float dz = fabsf(pos[3*i+2] - pos[3*j+2]);
        if (dx > RMAXF) dx = BOXF - dx;     // minimum-image fold
        if (dy > RMAXF) dy = BOXF - dy;
        if (dz > RMAXF) dz = BOXF - dz;
        const float dist = sqrtf(dx*dx + dy*dy + dz*dz);
        const float c = dist * inv_w;       // position in bin-width units
        float b0f = ceilf(c - 3.0f);        // +/-3 sigma window, 7 bins
        if (b0f < 0.0f) b0f = 0.0f;
        if (valid && dist > 0.0f && b0f <= 399.0f) {
            const int b0 = (int)b0f;
            const float u = c - b0f;        // u0 in [0, 3]
            float E = exp2f(C2E * u * u);
            float F = exp2f(C2F * (u - 0.5f));
            const int rmax = (NBINS - 1) - b0;
            #pragma unroll
            for (int r = 0; r < 7; ++r) {
                if (r <= rmax)
                    unsafeAtomicAdd(&hist[b0 + r], E);
                E *= F;
                F *= KE;
            }
        }
    }
    __syncthreads();
    for (int b = tid; b < NBINS; b += TPB)
        part[blockIdx.x * NBINS + b] = __float2bfloat16(hist[b]);
}

__global__ __launch_bounds__(512) void rdf_final(const __hip_bfloat16* __restrict__ part,
                                                 float* __restrict__ out) {
    __shared__ float ssum[8];
    const int t = threadIdx.x;

    float v = 0.0f;
    if (t < NBINS) {
        #pragma unroll 16
        for (int p = 0; p < NPART; ++p)
            v += __bfloat162float(part[p * NBINS + t]);
    }

    // total = sum over bins: wave(64) reduce then cross-wave via LDS
    float s = v;
    #pragma unroll
    for (int o = 32; o > 0; o >>= 1) s += __shfl_down(s, o, 64);
    if ((t & 63) == 0) ssum[t >> 6] = s;
    __syncthreads();
    if (t == 0) {
        float tot = 0.0f;
        #pragma unroll
        for (int w = 0; w < 8; ++w) tot += ssum[w];
        ssum[0] = tot;
    }
    __syncthreads();
    const float tot = ssum[0];

    if (t < NBINS) {
        const float cf = v / tot;
        out[t] = cf;                                   // count (normalized)
        // rdf = cf * V/vol_bin = cf * 400^3 / (3b^2+3b+1) (exact integer form)
        const float denom = (3.0f * t * t + 3.0f * t + 1.0f);
        out[801 + t] = cf * (400.0f * 400.0f * 400.0f) / denom;
    }
    if (t < NBINS + 1) {
        out[NBINS + t] = (float)t * (RMAXF / 400.0f);  // bins = linspace(0, R_MAX, 401)
    }
}

extern "C" void kernel_launch(void* const* d_in, const int* in_sizes, int n_in,
                              void* d_out, int out_size, void* d_ws, size_t ws_size,
                              hipStream_t stream) {
    const float* pos = (const float*)d_in[0];
    float* out = (float*)d_out;
    __hip_bfloat16* part = (__hip_bfloat16*)d_ws;   // NPART*NBINS bf16, overwritten each call

    rdf_hist<<<NPART, TPB, 0, stream>>>(pos, part);
    rdf_final<<<1, 512, 0, stream>>>(part, out);
}

// Round 11
// 16.267 us; speedup vs baseline: 1.2797x; 1.0202x over previous
//
#include <hip/hip_runtime.h>
#include <hip/hip_bf16.h>
#include <math.h>

// RDF with Gaussian smearing, N=512 points, 400 bins. Two dispatches:
// K1: 128 blocks x 256 thr histogram unordered pairs into LDS (Gaussian via
//     multiplicative recurrence, 6-bin window ~ +/-2.75 sigma), bf16 partials.
// K2: 1 block reduces 128 bf16 partials (bf16x2 loads), writes count/bins/rdf.
// out layout: count[0..399], bins[400..800] (401 vals), rdf[801..1200]
// R11 = R10 + 6-bin window + unguarded fast path + vectorized K2 reads.
#define NBINS 400
#define NPTS  512
#define RMAXF 13.635f
#define BOXF  (2.0f * RMAXF)
#define NPART 128
#define TPB   256
#define WIN   6

__global__ __launch_bounds__(TPB) void rdf_hist(const float* __restrict__ pos,
                                                __hip_bfloat16* __restrict__ part) {
    __shared__ float hist[NBINS];
    const int tid = threadIdx.x;
    for (int b = tid; b < NBINS; b += TPB) hist[b] = 0.0f;
    __syncthreads();

    const float inv_w = 399.0f / RMAXF;     // 1/width
    // E(b)=exp(-0.5*u^2), u = c-b (bin-width units). Recurrence along b:
    //   E <- E*F,  F <- F*e^-1,  E0=exp2(-0.5*log2e*u0^2), F0=exp2(log2e*(u0-0.5)).
    const float C2E = -0.72134752f;         // -0.5*log2(e)
    const float C2F = 1.44269504f;          // log2(e)
    const float KE  = 0.36787944f;          // e^-1

    // Unordered pairs (ordered histogram = 2x this; factor cancels in
    // count/total): slot p -> i = p>>8, k = (p&255)+1, j = (i+k) mod 512.
    // k==256 pairs appear for both endpoints; keep only i<256.
    const int total = NPTS * 256;           // 131072 slots
    for (int p = blockIdx.x * TPB + tid; p < total; p += NPART * TPB) {
        const int i = p >> 8;
        const int k = (p & 255) + 1;
        const bool valid = !(k == 256 && i >= 256);
        const int j = (i + k) & (NPTS - 1);
        float dx = fabsf(pos[3*i+0] - pos[3*j+0]);
        float dy = fabsf(pos[3*i+1] - pos[3*j+1]);
        float dz = fabsf(pos[3*i+2] - pos[3*j+2]);
        if (dx > RMAXF) dx = BOXF - dx;     // minimum-image fold
        if (dy > RMAXF) dy = BOXF - dy;
        if (dz > RMAXF) dz = BOXF - dz;
        const float dist = sqrtf(dx*dx + dy*dy + dz*dz);
        const float c = dist * inv_w;       // position in bin-width units
        float b0f = ceilf(c - 2.75f);       // ~+/-2.75 sigma window, 6 bins
        if (b0f < 0.0f) b0f = 0.0f;
        if (valid && dist > 0.0f && b0f <= 399.0f) {
            const int b0 = (int)b0f;
            const float u = c - b0f;        // u0 in [0, 2.75]
            float E = exp2f(C2E * u * u);
            float F = exp2f(C2F * (u - 0.5f));
            if (b0 <= NBINS - WIN) {        // fast path: full window in range
                #pragma unroll
                for (int r = 0; r < WIN; ++r) {
                    unsafeAtomicAdd(&hist[b0 + r], E);
                    E *= F;
                    F *= KE;
                }
            } else {                        // top-edge clip (~1.5% of pairs)
                const int rmax = (NBINS - 1) - b0;
                #pragma unroll
                for (int r = 0; r < WIN; ++r) {
                    if (r <= rmax)
                        unsafeAtomicAdd(&hist[b0 + r], E);
                    E *= F;
                    F *= KE;
                }
            }
        }
    }
    __syncthreads();
    for (int b = tid; b < NBINS; b += TPB)
        part[blockIdx.x * NBINS + b] = __float2bfloat16(hist[b]);
}

__global__ __launch_bounds__(512) void rdf_final(const __hip_bfloat16* __restrict__ part,
                                                 float* __restrict__ out) {
    __shared__ float ssum[8];
    const int t = threadIdx.x;

    // Thread t (t<200) owns bins 2t, 2t+1: bf16x2 vector loads, coalesced.
    float v0 = 0.0f, v1 = 0.0f;
    if (t < NBINS / 2) {
        const ushort2* p2 = (const ushort2*)part;
        #pragma unroll 16
        for (int p = 0; p < NPART; ++p) {
            const ushort2 u = p2[p * (NBINS / 2) + t];
            __hip_bfloat16_raw r0{u.x}, r1{u.y};
            v0 += __bfloat162float(__hip_bfloat16(r0));
            v1 += __bfloat162float(__hip_bfloat16(r1));
        }
    }

    // total = sum over bins: wave(64) reduce then cross-wave via LDS
    float s = v0 + v1;
    #pragma unroll
    for (int o = 32; o > 0; o >>= 1) s += __shfl_down(s, o, 64);
    if ((t & 63) == 0) ssum[t >> 6] = s;
    __syncthreads();
    if (t == 0) {
        float tot = 0.0f;
        #pragma unroll
        for (int w = 0; w < 8; ++w) tot += ssum[w];
        ssum[0] = tot;
    }
    __syncthreads();
    const float tot = ssum[0];

    if (t < NBINS / 2) {
        const int b0 = 2 * t, b1 = 2 * t + 1;
        const float cf0 = v0 / tot, cf1 = v1 / tot;
        out[b0] = cf0;                                 // count (normalized)
        out[b1] = cf1;
        // rdf = cf * V/vol_bin = cf * 400^3 / (3b^2+3b+1) (exact integer form)
        const float C3 = 400.0f * 400.0f * 400.0f;
        out[801 + b0] = cf0 * C3 / (3.0f*b0*b0 + 3.0f*b0 + 1.0f);
        out[801 + b1] = cf1 * C3 / (3.0f*b1*b1 + 3.0f*b1 + 1.0f);
    }
    if (t < NBINS + 1) {
        out[NBINS + t] = (float)t * (RMAXF / 400.0f);  // bins = linspace(0, R_MAX, 401)
    }
}

extern "C" void kernel_launch(void* const* d_in, const int* in_sizes, int n_in,
                              void* d_out, int out_size, void* d_ws, size_t ws_size,
                              hipStream_t stream) {
    const float* pos = (const float*)d_in[0];
    float* out = (float*)d_out;
    __hip_bfloat16* part = (__hip_bfloat16*)d_ws;   // NPART*NBINS bf16, overwritten each call

    rdf_hist<<<NPART, TPB, 0, stream>>>(pos, part);
    rdf_final<<<1, 512, 0, stream>>>(part, out);
}